// Round 3
// baseline (47420.959 us; speedup 1.0000x reference)
//
#include <hip/hip_runtime.h>
#include <hip/hip_bf16.h>

typedef __hip_bfloat16 bf16;
using bf16x8 = __attribute__((ext_vector_type(8))) short;   // 8 bf16 = 4 VGPRs
using f32x4  = __attribute__((ext_vector_type(4))) float;   // MFMA accumulator

#define B_   256
#define T1_  128
#define S_   128
#define A_   32
#define H_   1024
#define E_   1024
#define MIN_STD 0.1f
#define GRID_ 256
#define ASTRIDE 16   // ints between arrive slots (64B)

// ---- dtype-flexible load/store: isbf resolved at runtime from device probe ----
__device__ __forceinline__ float loadT(const void* p, int isbf, long idx) {
  return isbf ? __bfloat162float(((const bf16*)p)[idx]) : ((const float*)p)[idx];
}
__device__ __forceinline__ void storeT(void* p, int isbf, long idx, float v) {
  if (isbf) ((bf16*)p)[idx] = __float2bfloat16(v);
  else      ((float*)p)[idx] = v;
}
__device__ __forceinline__ float softplusf_(float x) {
  return fmaxf(x, 0.f) + log1pf(expf(-fabsf(x)));
}
__device__ __forceinline__ short f2bf_s(float v) {
  union { bf16 b; short s; } u; u.b = __float2bfloat16(v); return u.s;
}

// Probe: read nelem elements of a weight tensor (values ~N(0, 1/32)) AS bf16.
// f32 data read as bf16 -> garbage exponents / NaN. flag=1 => input is bf16.
// Also resets the grid-barrier state (arrive slots + phase) for this call.
__global__ void dtype_probe(const void* __restrict__ p, int nelem, int* __restrict__ flag,
                            int* __restrict__ arrive, int* __restrict__ phasep) {
  __shared__ int bad;
  if (threadIdx.x == 0) bad = 0;
  __syncthreads();
  const bf16* q = (const bf16*)p;
  int lbad = 0;
  for (int i = threadIdx.x; i < nelem; i += 256) {
    float v = __bfloat162float(q[i]);
    if (!(fabsf(v) <= 1e6f)) lbad = 1;
  }
  if (lbad) atomicOr(&bad, 1);
  for (int i = threadIdx.x; i < GRID_ * ASTRIDE; i += 256) arrive[i] = 0;
  __syncthreads();
  if (threadIdx.x == 0) { *flag = bad ? 0 : 1; *phasep = 0; }
}

// Split any tensor (dtype via flag) into hi/lo bf16 planes: v ~= h + l.
__global__ __launch_bounds__(256)
void split_plane(const void* __restrict__ src, long n, bf16* __restrict__ h,
                 bf16* __restrict__ l, const int* __restrict__ flagp) {
  const int F = *flagp;
  long i = (long)blockIdx.x * 256 + threadIdx.x;
  if (i < n) {
    float v = loadT(src, F, i);
    bf16 hv = __float2bfloat16(v);
    h[i] = hv;
    l[i] = __float2bfloat16(v - __bfloat162float(hv));
  }
}

// ---- manual grid barrier (graph-capture-safe; no cooperative launch) ----
// Each block release-stores its epoch into its own 64B slot; block 0's 256
// threads poll the 256 slots in parallel, then block 0 release-stores `phase`;
// other blocks acquire-spin on `phase`. Agent-scope fences give cross-XCD
// visibility of all data written before the barrier.
__device__ __forceinline__ void gbar(int* arrive, int* phasep, int epoch) {
  __syncthreads();
  if (blockIdx.x == 0) {
    if (threadIdx.x > 0) {
      int* a = arrive + threadIdx.x * ASTRIDE;
      while (__hip_atomic_load(a, __ATOMIC_RELAXED, __HIP_MEMORY_SCOPE_AGENT) < epoch)
        __builtin_amdgcn_s_sleep(1);
    }
    __threadfence();          // acquire arrivals / release own prior writes
    __syncthreads();
    if (threadIdx.x == 0)
      __hip_atomic_store(phasep, epoch, __ATOMIC_RELEASE, __HIP_MEMORY_SCOPE_AGENT);
  } else {
    if (threadIdx.x == 0) {
      __threadfence();        // release this block's prior writes
      __hip_atomic_store(arrive + blockIdx.x * ASTRIDE, epoch,
                         __ATOMIC_RELEASE, __HIP_MEMORY_SCOPE_AGENT);
      while (__hip_atomic_load(phasep, __ATOMIC_RELAXED, __HIP_MEMORY_SCOPE_AGENT) < epoch)
        __builtin_amdgcn_s_sleep(1);
      __threadfence();        // acquire everyone's writes
    }
    __syncthreads();
  }
}

// ---------------- persistent kernel ----------------
struct KP {
  const void *s0, *b0, *Act, *Obs, *npri, *npos;
  const void *b_sa, *b_ih, *b_hh, *b_bpri, *b_spri, *b_bpos, *b_spos;
  void* out;
  float *gi_f, *gh_f, *b_f, *catp_f, *catq_f, *hqo_f;
  bf16 *xh, *xl, *bh, *bl, *hph, *hpl, *hqh, *hql, *oh, *ol, *acth, *actl;
  const bf16 *wsah, *wsal, *wihh, *wihl, *whhh, *whhl;
  const bf16 *wprih, *wpril, *wsprih, *wspril, *wposh, *wposl, *wsposh, *wsposl;
  const int* flagp;
  int *arrive, *phasep;
};

struct GArg {
  const bf16 *ah, *al; int lda;
  const bf16 *wh, *wl; int ldw; int wbase;
  const void* bias; const float* cadd;
  float* cf; bf16 *ch; bf16 *cl; int ldc;
  int relu; int K; int nbx;
};

__device__ __forceinline__ void mfma3(f32x4& a, bf16x8 ah, bf16x8 al, bf16x8 wh, bf16x8 wl) {
  a = __builtin_amdgcn_mfma_f32_16x16x32_bf16(ah, wh, a, 0, 0, 0);
  a = __builtin_amdgcn_mfma_f32_16x16x32_bf16(al, wh, a, 0, 0, 0);
  a = __builtin_amdgcn_mfma_f32_16x16x32_bf16(ah, wl, a, 0, 0, 0);
}

// C/D layout (m89-verified): col = lane&15, row = (lane>>4)*4 + reg
__device__ __forceinline__ void epilogue(f32x4 (&acc)[4][4], int m0, int n0, int wm, int wn,
    int lane, int F, const void* bias, const float* cadd,
    float* cf, bf16* ch, bf16* cl, int ldc, int relu)
{
  const int lr = lane & 15;
  const int rb = m0 + wm + ((lane >> 4) << 2);
  #pragma unroll
  for (int j = 0; j < 4; ++j) {
    const int n = n0 + wn + 16 * j + lr;
    const float bv = bias ? loadT(bias, F, n) : 0.f;
    #pragma unroll
    for (int i = 0; i < 4; ++i) {
      #pragma unroll
      for (int r = 0; r < 4; ++r) {
        long o = (long)(rb + 16 * i + r) * ldc + n;
        float v = acc[i][j][r] + bv;
        if (cadd) v += cadd[o];
        if (relu) v = fmaxf(v, 0.f);
        if (cf) cf[o] = v;
        if (ch) {
          bf16 hb = __float2bfloat16(v);
          ch[o] = hb;
          cl[o] = __float2bfloat16(v - __bfloat162float(hb));
        }
      }
    }
  }
}

// Generic 128x128-tile TN GEMM, 4 waves, 4x4 fragments/wave, split-bf16 3-MFMA.
__device__ void run_gemm(const GArg& g, int tile, int F, int wm, int wn, int lr, int lk8, int lane) {
  const int m0 = (tile / g.nbx) * 128;
  const int n0 = (tile % g.nbx) * 128;
  const int r0 = m0 + wm + lr;
  const int c0 = n0 + wn + lr;
  f32x4 acc[4][4];
  #pragma unroll
  for (int i = 0; i < 4; ++i)
    #pragma unroll
    for (int j = 0; j < 4; ++j) acc[i][j] = (f32x4){0.f, 0.f, 0.f, 0.f};

  #pragma unroll 2
  for (int kt = 0; kt < g.K; kt += 32) {
    bf16x8 fah[4], fal[4], fwh[4], fwl[4];
    #pragma unroll
    for (int i = 0; i < 4; ++i) {
      long ao = (long)(r0 + 16 * i) * g.lda + kt + lk8;
      fah[i] = *(const bf16x8*)(g.ah + ao);
      fal[i] = *(const bf16x8*)(g.al + ao);
    }
    #pragma unroll
    for (int j = 0; j < 4; ++j) {
      long wo = (long)(c0 + 16 * j) * g.ldw + g.wbase + kt + lk8;
      fwh[j] = *(const bf16x8*)(g.wh + wo);
      fwl[j] = *(const bf16x8*)(g.wl + wo);
    }
    #pragma unroll
    for (int i = 0; i < 4; ++i)
      #pragma unroll
      for (int j = 0; j < 4; ++j)
        mfma3(acc[i][j], fah[i], fal[i], fwh[j], fwl[j]);
  }
  epilogue(acc, m0, n0, wm, wn, lane, F, g.bias, g.cadd, g.cf, g.ch, g.cl, g.ldc, g.relu);
}

// x = relu([s, a_t] @ W_sa^T + b_sa) with s recomputed inline from catq (t>0)
// or loaded from s0 (t==0). Out: split planes xh/xl.
__device__ void x_tile(const KP& p, int F, int t, int tile, int wm, int wn, int lr, int lk8, int lane) {
  const int m0 = (tile / 8) * 128;
  const int n0 = (tile % 8) * 128;
  const int r0 = m0 + wm + lr;
  const int c0 = n0 + wn + lr;
  f32x4 acc[4][4];
  #pragma unroll
  for (int i = 0; i < 4; ++i)
    #pragma unroll
    for (int j = 0; j < 4; ++j) acc[i][j] = (f32x4){0.f, 0.f, 0.f, 0.f};

  // segment 1: k in [0,128) = state s
  for (int kt = 0; kt < 128; kt += 32) {
    bf16x8 fah[4], fal[4], fwh[4], fwl[4];
    #pragma unroll
    for (int i = 0; i < 4; ++i) {
      const int r = r0 + 16 * i;
      const int k0 = kt + lk8;
      #pragma unroll
      for (int e = 0; e < 8; ++e) {
        const int kk = k0 + e;
        float v;
        if (t == 0) {
          v = loadT(p.s0, F, (long)r * S_ + kk);
        } else {
          float mu  = p.catq_f[(long)r * 256 + kk];
          float h2  = p.catq_f[(long)r * 256 + 128 + kk];
          float eps = loadT(p.npos, F, (long)r * (T1_ * S_) + (long)(t - 1) * S_ + kk);
          v = mu + (softplusf_(h2) + MIN_STD) * eps;
        }
        bf16 hb = __float2bfloat16(v);
        union { bf16 b; short s; } u; u.b = hb;
        fah[i][e] = u.s;
        fal[i][e] = f2bf_s(v - __bfloat162float(hb));
      }
    }
    #pragma unroll
    for (int j = 0; j < 4; ++j) {
      long wo = (long)(c0 + 16 * j) * (S_ + A_) + kt + lk8;
      fwh[j] = *(const bf16x8*)(p.wsah + wo);
      fwl[j] = *(const bf16x8*)(p.wsal + wo);
    }
    #pragma unroll
    for (int i = 0; i < 4; ++i)
      #pragma unroll
      for (int j = 0; j < 4; ++j)
        mfma3(acc[i][j], fah[i], fal[i], fwh[j], fwl[j]);
  }
  // segment 2: k in [128,160) = action a_t
  {
    bf16x8 fah[4], fal[4], fwh[4], fwl[4];
    #pragma unroll
    for (int i = 0; i < 4; ++i) {
      long ao = (long)(r0 + 16 * i) * (T1_ * A_) + (long)t * A_ + lk8;
      fah[i] = *(const bf16x8*)(p.acth + ao);
      fal[i] = *(const bf16x8*)(p.actl + ao);
    }
    #pragma unroll
    for (int j = 0; j < 4; ++j) {
      long wo = (long)(c0 + 16 * j) * (S_ + A_) + 128 + lk8;
      fwh[j] = *(const bf16x8*)(p.wsah + wo);
      fwl[j] = *(const bf16x8*)(p.wsal + wo);
    }
    #pragma unroll
    for (int i = 0; i < 4; ++i)
      #pragma unroll
      for (int j = 0; j < 4; ++j)
        mfma3(acc[i][j], fah[i], fal[i], fwh[j], fwl[j]);
  }
  epilogue(acc, m0, n0, wm, wn, lane, F, p.b_sa, nullptr, nullptr, p.xh, p.xl, H_, 1);
}

__device__ __forceinline__ void gru_elem(const KP& p, int F, int t, int idx) {
  int b = idx >> 10, j = idx & 1023;
  long g3 = (long)b * 3072;
  float ir  = p.gi_f[g3 + j],        hr = p.gh_f[g3 + j];
  float iz  = p.gi_f[g3 + 1024 + j], hz = p.gh_f[g3 + 1024 + j];
  float in_ = p.gi_f[g3 + 2048 + j], hn = p.gh_f[g3 + 2048 + j];
  float h = t ? p.b_f[idx] : loadT(p.b0, F, idx);
  float r = 1.f / (1.f + expf(-(ir + hr)));
  float z = 1.f / (1.f + expf(-(iz + hz)));
  float n = tanhf(in_ + r * hn);
  float v = (1.f - z) * n + z * h;
  storeT(p.out, F, (long)b * (T1_ * H_) + (long)t * H_ + j, v);
  p.b_f[idx] = v;
  bf16 hb = __float2bfloat16(v);
  p.bh[idx] = hb;
  p.bl[idx] = __float2bfloat16(v - __bfloat162float(hb));
}

__device__ __forceinline__ void sample_elem(const KP& p, int F, int t, int idx) {
  int b = idx >> 7, s = idx & 127;
  const long SZH = (long)B_ * T1_ * H_;
  const long SZS = (long)B_ * T1_ * S_;
  long nidx = (long)b * (T1_ * S_) + (long)t * S_ + s;
  long crow = (long)b * 256;
  float mu_p = p.catp_f[crow + s];
  float h2p  = p.catp_f[crow + 128 + s];
  float mu_q = p.catq_f[crow + s];
  float h2q  = p.catq_f[crow + 128 + s];
  float std_p = softplusf_(h2p) + MIN_STD;
  float std_q = softplusf_(h2q) + MIN_STD;
  float s_p = mu_p + std_p * loadT(p.npri, F, nidx);
  float s_q = mu_q + std_q * loadT(p.npos, F, nidx);
  storeT(p.out, F, SZH + 0 * SZS + nidx, s_p);
  storeT(p.out, F, SZH + 1 * SZS + nidx, mu_p);
  storeT(p.out, F, SZH + 2 * SZS + nidx, std_p);
  storeT(p.out, F, SZH + 3 * SZS + nidx, s_q);
  storeT(p.out, F, SZH + 4 * SZS + nidx, mu_q);
  storeT(p.out, F, SZH + 5 * SZS + nidx, std_q);
}

__global__ __launch_bounds__(256, 1) void fused_seq(KP p) {
  const int F    = *p.flagp;
  const int blk  = blockIdx.x;
  const int tid  = threadIdx.x;
  const int w    = tid >> 6;
  const int lane = tid & 63;
  const int wm   = (w >> 1) * 64;
  const int wn   = (w & 1) * 64;
  const int lr   = lane & 15;
  const int lk8  = (lane >> 4) * 8;

  int epoch = 0;
  #define GSYNC() gbar(p.arrive, p.phasep, ++epoch)

  // prologue: gh_0 = b0 @ W_hh^T + b_hh (from b0 split planes)
  {
    GArg g = { p.bh, p.bl, H_, p.whhh, p.whhl, H_, 0, p.b_hh, nullptr,
               p.gh_f, nullptr, nullptr, 3 * H_, 0, H_, 24 };
    if (blk < 48) run_gemm(g, blk, F, wm, wn, lr, lk8, lane);
  }
  GSYNC();

  for (int t = 0; t < T1_; ++t) {
    // ---- phase A: x-GEMM (16) | obs split (224) | sample t-1 (16) ----
    if (blk < 16) {
      x_tile(p, F, t, blk, wm, wn, lr, lk8, lane);
    } else if (blk < 240) {
      int pos = (blk - 16) * 256 + tid;
      for (int i = pos; i < B_ * E_; i += 224 * 256) {
        int b = i >> 10, j = i & 1023;
        float ov = loadT(p.Obs, F, (long)b * (T1_ * E_) + (long)t * E_ + j);
        bf16 hb = __float2bfloat16(ov);
        p.oh[i] = hb;
        p.ol[i] = __float2bfloat16(ov - __bfloat162float(hb));
      }
    } else if (t > 0) {
      int pos = (blk - 240) * 256 + tid;  // 4096 threads
      for (int i = pos; i < B_ * S_; i += 4096) sample_elem(p, F, t - 1, i);
    }
    GSYNC();

    // ---- phase B: gi (48) | hqo = o_t @ W_bpos[:,H:]^T + b_bpos (16) ----
    if (blk < 48) {
      GArg g = { p.xh, p.xl, H_, p.wihh, p.wihl, H_, 0, p.b_ih, nullptr,
                 p.gi_f, nullptr, nullptr, 3 * H_, 0, H_, 24 };
      run_gemm(g, blk, F, wm, wn, lr, lk8, lane);
    } else if (blk < 64) {
      GArg g = { p.oh, p.ol, E_, p.wposh, p.wposl, H_ + E_, H_, p.b_bpos, nullptr,
                 p.hqo_f, nullptr, nullptr, H_, 0, H_, 8 };
      run_gemm(g, blk - 48, F, wm, wn, lr, lk8, lane);
    }
    GSYNC();

    // ---- phase C: GRU elementwise ----
    {
      int pos = blk * 256 + tid;
      for (int i = pos; i < B_ * H_; i += GRID_ * 256) gru_elem(p, F, t, i);
    }
    GSYNC();

    // ---- phase D: hp (16) | hq (16, + hqo) | gh_{t+1} (48) ----
    if (blk < 16) {
      GArg g = { p.bh, p.bl, H_, p.wprih, p.wpril, H_, 0, p.b_bpri, nullptr,
                 nullptr, p.hph, p.hpl, H_, 1, H_, 8 };
      run_gemm(g, blk, F, wm, wn, lr, lk8, lane);
    } else if (blk < 32) {
      GArg g = { p.bh, p.bl, H_, p.wposh, p.wposl, H_ + E_, 0, nullptr, p.hqo_f,
                 nullptr, p.hqh, p.hql, H_, 1, H_, 8 };
      run_gemm(g, blk - 16, F, wm, wn, lr, lk8, lane);
    } else if (blk < 80) {
      GArg g = { p.bh, p.bl, H_, p.whhh, p.whhl, H_, 0, p.b_hh, nullptr,
                 p.gh_f, nullptr, nullptr, 3 * H_, 0, H_, 24 };
      run_gemm(g, blk - 32, F, wm, wn, lr, lk8, lane);
    }
    GSYNC();

    // ---- phase E: catp (4) | catq (4) ----
    if (blk < 4) {
      GArg g = { p.hph, p.hpl, H_, p.wsprih, p.wspril, H_, 0, p.b_spri, nullptr,
                 p.catp_f, nullptr, nullptr, 2 * S_, 0, H_, 2 };
      run_gemm(g, blk, F, wm, wn, lr, lk8, lane);
    } else if (blk < 8) {
      GArg g = { p.hqh, p.hql, H_, p.wsposh, p.wsposl, H_, 0, p.b_spos, nullptr,
                 p.catq_f, nullptr, nullptr, 2 * S_, 0, H_, 2 };
      run_gemm(g, blk - 4, F, wm, wn, lr, lk8, lane);
    }
    GSYNC();
  }

  // final sample for t = T1-1
  {
    int pos = blk * 256 + tid;
    if (pos < B_ * S_) sample_elem(p, F, T1_ - 1, pos);
  }
  #undef GSYNC
}

extern "C" void kernel_launch(void* const* d_in, const int* in_sizes, int n_in,
                              void* d_out, int out_size, void* d_ws, size_t ws_size,
                              hipStream_t stream) {
  const void* s0     = d_in[0];
  const void* b0     = d_in[1];
  const void* Act    = d_in[2];
  const void* Obs    = d_in[3];
  const void* npri   = d_in[4];
  const void* npos   = d_in[5];
  const void* W_sa   = d_in[6];
  const void* b_sa   = d_in[7];
  const void* W_ih   = d_in[8];
  const void* W_hh   = d_in[9];
  const void* b_ih   = d_in[10];
  const void* b_hh   = d_in[11];
  const void* W_bpri = d_in[12];
  const void* b_bpri = d_in[13];
  const void* W_spri = d_in[14];
  const void* b_spri = d_in[15];
  const void* W_bpos = d_in[16];
  const void* b_bpos = d_in[17];
  const void* W_spos = d_in[18];
  const void* b_spos = d_in[19];
  (void)in_sizes; (void)n_in; (void)out_size; (void)ws_size;

  // ---- workspace carve (~59 MB; all buffers 256B aligned) ----
  char* base = (char*)d_ws;
  size_t off = 0;
  auto carve = [&](size_t bytes) {
    void* q = base + off;
    off = (off + bytes + 255) & ~(size_t)255;
    return q;
  };
  float* gi_f   = (float*)carve(sizeof(float) * B_ * 3 * H_);
  float* gh_f   = (float*)carve(sizeof(float) * B_ * 3 * H_);
  float* b_f    = (float*)carve(sizeof(float) * B_ * H_);
  float* catp_f = (float*)carve(sizeof(float) * B_ * 2 * S_);
  float* catq_f = (float*)carve(sizeof(float) * B_ * 2 * S_);
  float* hqo_f  = (float*)carve(sizeof(float) * B_ * H_);
  int*   flagp  = (int*)carve(256);
  int*   arrive = (int*)carve(sizeof(int) * GRID_ * ASTRIDE);
  int*   phasep = (int*)carve(256);
  auto plane = [&](size_t n) { return (bf16*)carve(2 * n); };
  bf16 *xh = plane((size_t)B_ * H_),  *xl = plane((size_t)B_ * H_);
  bf16 *bh = plane((size_t)B_ * H_),  *bl = plane((size_t)B_ * H_);
  bf16 *hph = plane((size_t)B_ * H_), *hpl = plane((size_t)B_ * H_);
  bf16 *hqh = plane((size_t)B_ * H_), *hql = plane((size_t)B_ * H_);
  bf16 *oh = plane((size_t)B_ * E_),  *ol = plane((size_t)B_ * E_);
  bf16 *acth = plane((size_t)B_ * T1_ * A_), *actl = plane((size_t)B_ * T1_ * A_);
  bf16 *wsah  = plane((size_t)H_ * (S_ + A_)), *wsal  = plane((size_t)H_ * (S_ + A_));
  bf16 *wihh  = plane((size_t)3 * H_ * H_),    *wihl  = plane((size_t)3 * H_ * H_);
  bf16 *whhh  = plane((size_t)3 * H_ * H_),    *whhl  = plane((size_t)3 * H_ * H_);
  bf16 *wprih = plane((size_t)H_ * H_),        *wpril = plane((size_t)H_ * H_);
  bf16 *wsprih = plane((size_t)2 * S_ * H_),   *wspril = plane((size_t)2 * S_ * H_);
  bf16 *wposh = plane((size_t)H_ * (H_ + E_)), *wposl = plane((size_t)H_ * (H_ + E_));
  bf16 *wsposh = plane((size_t)2 * S_ * H_),   *wsposl = plane((size_t)2 * S_ * H_);

  dim3 blk(256);

  // ---- setup: dtype probe (+ barrier reset) + one-time splits ----
  dtype_probe<<<dim3(1), blk, 0, stream>>>(W_ih, 8192, flagp, arrive, phasep);
  auto split = [&](const void* src, size_t n, bf16* h, bf16* l) {
    split_plane<<<dim3((unsigned)((n + 255) / 256)), blk, 0, stream>>>(src, (long)n, h, l, flagp);
  };
  split(W_sa,   (size_t)H_ * (S_ + A_), wsah, wsal);
  split(W_ih,   (size_t)3 * H_ * H_,    wihh, wihl);
  split(W_hh,   (size_t)3 * H_ * H_,    whhh, whhl);
  split(W_bpri, (size_t)H_ * H_,        wprih, wpril);
  split(W_spri, (size_t)2 * S_ * H_,    wsprih, wspril);
  split(W_bpos, (size_t)H_ * (H_ + E_), wposh, wposl);
  split(W_spos, (size_t)2 * S_ * H_,    wsposh, wsposl);
  split(b0,  (size_t)B_ * H_,           bh, bl);
  split(Act, (size_t)B_ * T1_ * A_,     acth, actl);

  // ---- one persistent kernel (normal launch; manual grid barriers) ----
  KP kp;
  kp.s0 = s0; kp.b0 = b0; kp.Act = Act; kp.Obs = Obs; kp.npri = npri; kp.npos = npos;
  kp.b_sa = b_sa; kp.b_ih = b_ih; kp.b_hh = b_hh; kp.b_bpri = b_bpri;
  kp.b_spri = b_spri; kp.b_bpos = b_bpos; kp.b_spos = b_spos;
  kp.out = d_out;
  kp.gi_f = gi_f; kp.gh_f = gh_f; kp.b_f = b_f;
  kp.catp_f = catp_f; kp.catq_f = catq_f; kp.hqo_f = hqo_f;
  kp.xh = xh; kp.xl = xl; kp.bh = bh; kp.bl = bl;
  kp.hph = hph; kp.hpl = hpl; kp.hqh = hqh; kp.hql = hql;
  kp.oh = oh; kp.ol = ol; kp.acth = acth; kp.actl = actl;
  kp.wsah = wsah; kp.wsal = wsal; kp.wihh = wihh; kp.wihl = wihl;
  kp.whhh = whhh; kp.whhl = whhl; kp.wprih = wprih; kp.wpril = wpril;
  kp.wsprih = wsprih; kp.wspril = wspril; kp.wposh = wposh; kp.wposl = wposl;
  kp.wsposh = wsposh; kp.wsposl = wsposl;
  kp.flagp = flagp;
  kp.arrive = arrive; kp.phasep = phasep;

  fused_seq<<<dim3(GRID_), blk, 0, stream>>>(kp);
}